// Round 3
// baseline (809.177 us; speedup 1.0000x reference)
//
#include <hip/hip_runtime.h>
#include <math.h>

#define N 1024
#define C 8
#define DIM 128
#define K 3
#define LBP_LOOPS 10
#define DAMP 0.5f

#define TI 16
#define TJ 16
#define DCH 32
#define ROWSTRIDE 257  // 8*32+1, odd -> conflict-free lane strides
#define SEG 32

// ---------------- small utility kernels ----------------

__global__ void zero4_kernel(float4* __restrict__ p, int n4) {
    int x = blockIdx.x * blockDim.x + threadIdx.x;
    if (x < n4) p[x] = make_float4(0.f, 0.f, 0.f, 0.f);
}

// psi[i,c] = sum_d E[i,c,d]*B[d]*Fc[i,d]
__global__ void psi_kernel(const float* __restrict__ E, const float* __restrict__ Fc,
                           const float* __restrict__ B, float* __restrict__ psi) {
    int x = blockIdx.x * blockDim.x + threadIdx.x; // [0, N*C)
    if (x >= N * C) return;
    int i = x / C;
    const float* e = E + (size_t)x * DIM;
    const float* fc = Fc + (size_t)i * DIM;
    float s = 0.f;
#pragma unroll 8
    for (int d = 0; d < DIM; ++d) s = fmaf(e[d] * B[d], fc[d], s);
    psi[x] = s;
}

// ---------------- phi tile computation (shared core) ----------------

struct PhiShared {
    float sFi[TI * 129];
    float sFj[TJ * 129];
    float sD[K * DIM];
    float sR[K * DIM];
    float sEi[TI * ROWSTRIDE];
    float sEj[TJ * ROWSTRIDE];
};

// Computes acc[ci][cj] = phi[i0+il, j0+jl, ci, cj] for this thread's pair.
__device__ __forceinline__ void phi_compute(
    PhiShared& sh,
    const float* __restrict__ E, const float* __restrict__ F,
    const float* __restrict__ R, const float* __restrict__ D,
    int i0, int j0, int il, int jl, int tid, float acc[C][C])
{
    for (int t = tid; t < TI * DIM; t += 256) {
        int r = t / DIM, d = t % DIM;
        sh.sFi[r * 129 + d] = F[(size_t)(i0 + r) * DIM + d];
        sh.sFj[r * 129 + d] = F[(size_t)(j0 + r) * DIM + d];
    }
    for (int t = tid; t < K * DIM; t += 256) { sh.sD[t] = D[t]; sh.sR[t] = R[t]; }
    __syncthreads();

    // logits -> a (softmax over K=3)
    float lg0 = 0.f, lg1 = 0.f, lg2 = 0.f;
#pragma unroll 4
    for (int d = 0; d < DIM; ++d) {
        float ff = sh.sFi[il * 129 + d] * sh.sFj[jl * 129 + d];
        lg0 = fmaf(ff, sh.sD[d], lg0);
        lg1 = fmaf(ff, sh.sD[DIM + d], lg1);
        lg2 = fmaf(ff, sh.sD[2 * DIM + d], lg2);
    }
    const float scale = 0.088388347648318447f; // 1/sqrt(128)
    lg0 *= scale; lg1 *= scale; lg2 *= scale;
    float mx = fmaxf(fmaxf(lg0, lg1), lg2);
    float e0 = __expf(lg0 - mx), e1 = __expf(lg1 - mx), e2 = __expf(lg2 - mx);
    float inv = 1.f / (e0 + e1 + e2);
    float a0 = e0 * inv, a1 = e1 * inv, a2 = e2 * inv;

#pragma unroll
    for (int ci = 0; ci < C; ++ci)
#pragma unroll
        for (int cj = 0; cj < C; ++cj) acc[ci][cj] = 0.f;

    for (int d0 = 0; d0 < DIM; d0 += DCH) {
        __syncthreads();
        for (int t = tid; t < TI * C * DCH; t += 256) {
            int loc = t >> 8;
            int ci = (t >> 5) & 7;
            int d = t & 31;
            sh.sEi[loc * ROWSTRIDE + ci * DCH + d] = E[((size_t)(i0 + loc) * C + ci) * DIM + d0 + d];
            sh.sEj[loc * ROWSTRIDE + ci * DCH + d] = E[((size_t)(j0 + loc) * C + ci) * DIM + d0 + d];
        }
        __syncthreads();
#pragma unroll 4
        for (int d = 0; d < DCH; ++d) {
            float rw = a0 * sh.sR[d0 + d] + a1 * sh.sR[DIM + d0 + d] + a2 * sh.sR[2 * DIM + d0 + d];
            float ei[C], ej[C];
#pragma unroll
            for (int ci = 0; ci < C; ++ci) ei[ci] = sh.sEi[il * ROWSTRIDE + ci * DCH + d] * rw;
#pragma unroll
            for (int cj = 0; cj < C; ++cj) ej[cj] = sh.sEj[jl * ROWSTRIDE + cj * DCH + d];
#pragma unroll
            for (int ci = 0; ci < C; ++ci)
#pragma unroll
                for (int cj = 0; cj < C; ++cj)
                    acc[ci][cj] = fmaf(ei[ci], ej[cj], acc[ci][cj]);
        }
    }
}

__global__ __launch_bounds__(256) void phi_f32_kernel(
    const float* __restrict__ E, const float* __restrict__ F,
    const float* __restrict__ R, const float* __restrict__ D,
    float* __restrict__ phi)
{
    __shared__ PhiShared sh;
    int tid = threadIdx.x;
    int i0 = blockIdx.y * TI, j0 = blockIdx.x * TJ;
    int il = tid >> 4, jl = tid & 15;
    float acc[C][C];
    phi_compute(sh, E, F, R, D, i0, j0, il, jl, tid, acc);
    float* out = phi + ((size_t)(i0 + il) * N + (j0 + jl)) * (C * C);
#pragma unroll
    for (int ci = 0; ci < C; ++ci)
#pragma unroll
        for (int cj = 0; cj < C; ++cj) out[ci * C + cj] = acc[ci][cj];
}

// int16 phi with per-pair scale: q = rint(phi * 32767/absmax), scale = absmax/32767
__global__ __launch_bounds__(256) void phi_i16_kernel(
    const float* __restrict__ E, const float* __restrict__ F,
    const float* __restrict__ R, const float* __restrict__ D,
    short* __restrict__ phiQ, float* __restrict__ pscale)
{
    __shared__ PhiShared sh;
    int tid = threadIdx.x;
    int i0 = blockIdx.y * TI, j0 = blockIdx.x * TJ;
    int il = tid >> 4, jl = tid & 15;
    float acc[C][C];
    phi_compute(sh, E, F, R, D, i0, j0, il, jl, tid, acc);

    float amax = 0.f;
#pragma unroll
    for (int ci = 0; ci < C; ++ci)
#pragma unroll
        for (int cj = 0; cj < C; ++cj) amax = fmaxf(amax, fabsf(acc[ci][cj]));
    float qs = (amax > 0.f) ? (32767.0f / amax) : 1.0f;

    size_t pair = (size_t)(i0 + il) * N + (j0 + jl);
    pscale[pair] = (amax > 0.f) ? (amax / 32767.0f) : 0.f;

    int4* out = (int4*)(phiQ + pair * (C * C));
#pragma unroll
    for (int ci = 0; ci < C; ++ci) {
        int q[C];
#pragma unroll
        for (int cj = 0; cj < C; ++cj) q[cj] = (int)rintf(acc[ci][cj] * qs);
        int4 v;
        v.x = (q[0] & 0xFFFF) | (q[1] << 16);
        v.y = (q[2] & 0xFFFF) | (q[3] << 16);
        v.z = (q[4] & 0xFFFF) | (q[5] << 16);
        v.w = (q[6] & 0xFFFF) | (q[7] << 16);
        out[ci] = v;
    }
}

// ---------------- column sums ----------------

__global__ void colsum_part(const float* __restrict__ mbar, float* __restrict__ part) {
    int x = blockIdx.x * blockDim.x + threadIdx.x; // [0, N*C)
    int seg = blockIdx.y;                          // [0, SEG)
    float s = 0.f;
    int s0 = seg * (N / SEG);
#pragma unroll 4
    for (int k = 0; k < N / SEG; ++k) s += mbar[(size_t)(s0 + k) * N * C + x];
    part[(size_t)seg * (N * C) + x] = s;
}

__global__ void colsum_fin(const float* __restrict__ part, const float* __restrict__ psi,
                           float* __restrict__ incpsi) {
    int x = blockIdx.x * blockDim.x + threadIdx.x;
    if (x >= N * C) return;
    float s = psi[x];
#pragma unroll
    for (int g = 0; g < SEG; ++g) s += part[(size_t)g * (N * C) + x];
    incpsi[x] = s;
}

// ---------------- message update core ----------------

__device__ __forceinline__ void msg_softmax_store(
    const float sc[C], const float ph[C][C],
    const float* __restrict__ mij, float* __restrict__ mn)
{
    float msg[C];
#pragma unroll
    for (int cj = 0; cj < C; ++cj) msg[cj] = sc[0] + ph[0][cj];
#pragma unroll
    for (int ci = 1; ci < C; ++ci)
#pragma unroll
        for (int cj = 0; cj < C; ++cj) msg[cj] = fmaxf(msg[cj], sc[ci] + ph[ci][cj]);

    float mx = msg[0];
#pragma unroll
    for (int cj = 1; cj < C; ++cj) mx = fmaxf(mx, msg[cj]);
    float e[C], s = 0.f;
#pragma unroll
    for (int cj = 0; cj < C; ++cj) { e[cj] = __expf(msg[cj] - mx); s += e[cj]; }
    float inv = DAMP / s;
#pragma unroll
    for (int cj = 0; cj < C; ++cj)
        mn[cj] = __logf(fmaf(e[cj], inv, (1.f - DAMP) * __expf(mij[cj])));
}

__global__ __launch_bounds__(256) void lbp_f32(
    const float* __restrict__ phi, const float* __restrict__ mprev,
    float* __restrict__ mnext, const float* __restrict__ incpsi)
{
    int i = blockIdx.y;
    int j = blockIdx.x * 256 + threadIdx.x;
    size_t pij = (size_t)i * N + j, pji = (size_t)j * N + i;

    const float* mji = mprev + pji * C;
    float sc[C];
#pragma unroll
    for (int ci = 0; ci < C; ++ci) sc[ci] = incpsi[i * C + ci] - mji[ci];

    float ph[C][C];
    const float4* p4 = (const float4*)(phi + pij * (C * C));
#pragma unroll
    for (int ci = 0; ci < C; ++ci) {
        float4 a = p4[2 * ci], b = p4[2 * ci + 1];
        ph[ci][0] = a.x; ph[ci][1] = a.y; ph[ci][2] = a.z; ph[ci][3] = a.w;
        ph[ci][4] = b.x; ph[ci][5] = b.y; ph[ci][6] = b.z; ph[ci][7] = b.w;
    }
    msg_softmax_store(sc, ph, mprev + pij * C, mnext + pij * C);
}

__global__ __launch_bounds__(256) void lbp_i16(
    const short* __restrict__ phiQ, const float* __restrict__ pscale,
    const float* __restrict__ mprev, float* __restrict__ mnext,
    const float* __restrict__ incpsi)
{
    int i = blockIdx.y;
    int j = blockIdx.x * 256 + threadIdx.x;
    size_t pij = (size_t)i * N + j, pji = (size_t)j * N + i;

    const float* mji = mprev + pji * C;
    float sc[C];
#pragma unroll
    for (int ci = 0; ci < C; ++ci) sc[ci] = incpsi[i * C + ci] - mji[ci];

    float s = pscale[pij];
    float ph[C][C];
    const int4* p4 = (const int4*)(phiQ + pij * (C * C));
#pragma unroll
    for (int ci = 0; ci < C; ++ci) {
        int4 v = p4[ci];
        ph[ci][0] = (float)((int)(short)(v.x & 0xFFFF)) * s;
        ph[ci][1] = (float)(v.x >> 16) * s;
        ph[ci][2] = (float)((int)(short)(v.y & 0xFFFF)) * s;
        ph[ci][3] = (float)(v.y >> 16) * s;
        ph[ci][4] = (float)((int)(short)(v.z & 0xFFFF)) * s;
        ph[ci][5] = (float)(v.z >> 16) * s;
        ph[ci][6] = (float)((int)(short)(v.w & 0xFFFF)) * s;
        ph[ci][7] = (float)(v.w >> 16) * s;
    }
    msg_softmax_store(sc, ph, mprev + pij * C, mnext + pij * C);
}

// PATH C: recompute phi tile fused with the message update (no phi buffer)
__global__ __launch_bounds__(256) void lbp_fused(
    const float* __restrict__ E, const float* __restrict__ F,
    const float* __restrict__ R, const float* __restrict__ D,
    const float* __restrict__ mprev, float* __restrict__ mnext,
    const float* __restrict__ incpsi)
{
    __shared__ PhiShared sh;
    int tid = threadIdx.x;
    int i0 = blockIdx.y * TI, j0 = blockIdx.x * TJ;
    int il = tid >> 4, jl = tid & 15;
    float acc[C][C];
    phi_compute(sh, E, F, R, D, i0, j0, il, jl, tid, acc);

    int i = i0 + il, j = j0 + jl;
    size_t pij = (size_t)i * N + j, pji = (size_t)j * N + i;
    const float* mji = mprev + pji * C;
    float sc[C];
#pragma unroll
    for (int ci = 0; ci < C; ++ci) sc[ci] = incpsi[i * C + ci] - mji[ci];
    msg_softmax_store(sc, acc, mprev + pij * C, mnext + pij * C);
}

// out[i,:] = softmax(psi + incoming - mbar[i,i,:])
__global__ void final_kernel(const float* __restrict__ incpsi, const float* __restrict__ mbar,
                             float* __restrict__ out) {
    int i = blockIdx.x * blockDim.x + threadIdx.x;
    if (i >= N) return;
    float u[C];
    float mx = -1e30f;
#pragma unroll
    for (int c = 0; c < C; ++c) {
        u[c] = incpsi[i * C + c] - mbar[((size_t)i * N + i) * C + c];
        mx = fmaxf(mx, u[c]);
    }
    float s = 0.f;
#pragma unroll
    for (int c = 0; c < C; ++c) { u[c] = __expf(u[c] - mx); s += u[c]; }
    float inv = 1.f / s;
#pragma unroll
    for (int c = 0; c < C; ++c) out[i * C + c] = u[c] * inv;
}

// ---------------- host ----------------

extern "C" void kernel_launch(void* const* d_in, const int* in_sizes, int n_in,
                              void* d_out, int out_size, void* d_ws, size_t ws_size,
                              hipStream_t stream) {
    const float* E  = (const float*)d_in[0];
    const float* F  = (const float*)d_in[1];
    const float* Fc = (const float*)d_in[2];
    const float* B  = (const float*)d_in[3];
    const float* R  = (const float*)d_in[4];
    const float* D  = (const float*)d_in[5];
    float* out = (float*)d_out;

    const size_t PHI_F32 = 268435456ull;  // N*N*C*C*4
    const size_t PHI_I16 = 134217728ull;  // N*N*C*C*2
    const size_t PSCALE  = 4194304ull;    // N*N*4
    const size_t MBAR    = 33554432ull;   // N*N*C*4
    const size_t SMALL   = 65536ull + 1048576ull; // psi+incpsi + part
    const size_t needA = PHI_F32 + 2 * MBAR + SMALL;          // ~336.7 MB
    const size_t needQ = PHI_I16 + PSCALE + 2 * MBAR + SMALL; // ~206.6 MB

    int path = (ws_size >= needA) ? 0 : (ws_size >= needQ) ? 1 : 2;

    char* p = (char*)d_ws;
    size_t off = (path == 0) ? PHI_F32 : (path == 1) ? (PHI_I16 + PSCALE) : 0;
    float* phiF   = (float*)p;
    short* phiQ   = (short*)p;
    float* pscale = (float*)(p + PHI_I16);
    float* mbar0 = (float*)(p + off);
    float* mbar1 = (float*)(p + off + MBAR);
    float* psi    = (float*)(p + off + 2 * MBAR);
    float* incpsi = psi + N * C;
    float* part   = (float*)(p + off + 2 * MBAR + 65536ull);

    psi_kernel<<<dim3((N * C + 255) / 256), 256, 0, stream>>>(E, Fc, B, psi);
    if (path == 0)
        phi_f32_kernel<<<dim3(N / TJ, N / TI), 256, 0, stream>>>(E, F, R, D, phiF);
    else if (path == 1)
        phi_i16_kernel<<<dim3(N / TJ, N / TI), 256, 0, stream>>>(E, F, R, D, phiQ, pscale);

    zero4_kernel<<<dim3((N * N * C / 4 + 255) / 256), 256, 0, stream>>>((float4*)mbar0, N * N * C / 4);

    float* cur = mbar0;
    float* nxt = mbar1;
    for (int it = 0; it < LBP_LOOPS; ++it) {
        colsum_part<<<dim3((N * C) / 256, SEG), 256, 0, stream>>>(cur, part);
        colsum_fin<<<dim3((N * C) / 256), 256, 0, stream>>>(part, psi, incpsi);
        if (path == 0)
            lbp_f32<<<dim3(N / 256, N), 256, 0, stream>>>(phiF, cur, nxt, incpsi);
        else if (path == 1)
            lbp_i16<<<dim3(N / 256, N), 256, 0, stream>>>(phiQ, pscale, cur, nxt, incpsi);
        else
            lbp_fused<<<dim3(N / TJ, N / TI), 256, 0, stream>>>(E, F, R, D, cur, nxt, incpsi);
        float* t = cur; cur = nxt; nxt = t;
    }
    colsum_part<<<dim3((N * C) / 256, SEG), 256, 0, stream>>>(cur, part);
    colsum_fin<<<dim3((N * C) / 256), 256, 0, stream>>>(part, psi, incpsi);
    final_kernel<<<dim3((N + 255) / 256), 256, 0, stream>>>(incpsi, cur, out);
}

// Round 4
// 730.863 us; speedup vs baseline: 1.1072x; 1.1072x over previous
//
#include <hip/hip_runtime.h>
#include <math.h>

#define N 1024
#define C 8
#define DIM 128
#define K 3
#define LBP_LOOPS 10
#define DAMP 0.5f

#define TI 16
#define TJ 16
#define DCH 32
#define ESTRIDE 260   // 8*32+4, float4-aligned rows, banks spread 4-apart
#define FSTRIDE 129
#define SEG 32

// ---------------- small utility kernels ----------------

__global__ void zero4_kernel(float4* __restrict__ p, int n4) {
    int x = blockIdx.x * blockDim.x + threadIdx.x;
    if (x < n4) p[x] = make_float4(0.f, 0.f, 0.f, 0.f);
}

// psi[i,c] = sum_d E[i,c,d]*B[d]*Fc[i,d]
__global__ void psi_kernel(const float* __restrict__ E, const float* __restrict__ Fc,
                           const float* __restrict__ B, float* __restrict__ psi) {
    int x = blockIdx.x * blockDim.x + threadIdx.x; // [0, N*C)
    if (x >= N * C) return;
    int i = x / C;
    const float* e = E + (size_t)x * DIM;
    const float* fc = Fc + (size_t)i * DIM;
    float s = 0.f;
#pragma unroll 8
    for (int d = 0; d < DIM; ++d) s = fmaf(e[d] * B[d], fc[d], s);
    psi[x] = s;
}

// ---------------- phi tile computation (shared core) ----------------

// Union layout: phase 1 uses sU as sFi/sFj (stride 129); phase 2 reuses it
// as sEi/sEj (stride 260). 2*16*260*4 + 2*K*DIM*4 = 36,352 B -> 4 blocks/CU.
struct PhiShared {
    float sU[2 * TI * ESTRIDE];
    float sD[K * DIM];
    float sR[K * DIM];
};

__device__ __forceinline__ void phi_compute(
    PhiShared& sh,
    const float* __restrict__ E, const float* __restrict__ F,
    const float* __restrict__ R, const float* __restrict__ D,
    int i0, int j0, int il, int jl, int tid, float acc[C][C])
{
    float* sFi = sh.sU;
    float* sFj = sh.sU + TI * FSTRIDE;
    float* sEi = sh.sU;
    float* sEj = sh.sU + TI * ESTRIDE;

    for (int t = tid; t < TI * DIM; t += 256) {
        int r = t / DIM, d = t % DIM;
        sFi[r * FSTRIDE + d] = F[(size_t)(i0 + r) * DIM + d];
        sFj[r * FSTRIDE + d] = F[(size_t)(j0 + r) * DIM + d];
    }
    for (int t = tid; t < K * DIM; t += 256) { sh.sD[t] = D[t]; sh.sR[t] = R[t]; }
    __syncthreads();

    // logits -> a (softmax over K=3)
    float lg0 = 0.f, lg1 = 0.f, lg2 = 0.f;
#pragma unroll 4
    for (int d = 0; d < DIM; ++d) {
        float ff = sFi[il * FSTRIDE + d] * sFj[jl * FSTRIDE + d];
        lg0 = fmaf(ff, sh.sD[d], lg0);
        lg1 = fmaf(ff, sh.sD[DIM + d], lg1);
        lg2 = fmaf(ff, sh.sD[2 * DIM + d], lg2);
    }
    const float scale = 0.088388347648318447f; // 1/sqrt(128)
    lg0 *= scale; lg1 *= scale; lg2 *= scale;
    float mx = fmaxf(fmaxf(lg0, lg1), lg2);
    float e0 = __expf(lg0 - mx), e1 = __expf(lg1 - mx), e2 = __expf(lg2 - mx);
    float inv = 1.f / (e0 + e1 + e2);
    float a0 = e0 * inv, a1 = e1 * inv, a2 = e2 * inv;

#pragma unroll
    for (int ci = 0; ci < C; ++ci)
#pragma unroll
        for (int cj = 0; cj < C; ++cj) acc[ci][cj] = 0.f;

    for (int d0 = 0; d0 < DIM; d0 += DCH) {
        __syncthreads();  // all threads done reading sU (logits or prev chunk)
        for (int t = tid; t < TI * C * DCH; t += 256) {
            int loc = t >> 8;
            int ci = (t >> 5) & 7;
            int d = t & 31;
            sEi[loc * ESTRIDE + ci * DCH + d] = E[((size_t)(i0 + loc) * C + ci) * DIM + d0 + d];
            sEj[loc * ESTRIDE + ci * DCH + d] = E[((size_t)(j0 + loc) * C + ci) * DIM + d0 + d];
        }
        __syncthreads();
#pragma unroll 4
        for (int d = 0; d < DCH; ++d) {
            float rw = a0 * sh.sR[d0 + d] + a1 * sh.sR[DIM + d0 + d] + a2 * sh.sR[2 * DIM + d0 + d];
            float ei[C], ej[C];
#pragma unroll
            for (int ci = 0; ci < C; ++ci) ei[ci] = sEi[il * ESTRIDE + ci * DCH + d] * rw;
#pragma unroll
            for (int cj = 0; cj < C; ++cj) ej[cj] = sEj[jl * ESTRIDE + cj * DCH + d];
#pragma unroll
            for (int ci = 0; ci < C; ++ci)
#pragma unroll
                for (int cj = 0; cj < C; ++cj)
                    acc[ci][cj] = fmaf(ei[ci], ej[cj], acc[ci][cj]);
        }
    }
}

// int16 phi with per-pair scale, upper triangle only (phi[j,i] = phi[i,j]^T)
__global__ __launch_bounds__(256) void phi_i16_sym_kernel(
    const float* __restrict__ E, const float* __restrict__ F,
    const float* __restrict__ R, const float* __restrict__ D,
    short* __restrict__ phiQ, float* __restrict__ pscale)
{
    int i0 = blockIdx.y * TI, j0 = blockIdx.x * TJ;
    if (i0 > j0) return;  // strictly-below-diagonal tile
    __shared__ PhiShared sh;
    int tid = threadIdx.x;
    int il = tid >> 4, jl = tid & 15;
    float acc[C][C];
    phi_compute(sh, E, F, R, D, i0, j0, il, jl, tid, acc);

    float amax = 0.f;
#pragma unroll
    for (int ci = 0; ci < C; ++ci)
#pragma unroll
        for (int cj = 0; cj < C; ++cj) amax = fmaxf(amax, fabsf(acc[ci][cj]));
    float qs = (amax > 0.f) ? (32767.0f / amax) : 1.0f;

    size_t pair = (size_t)(i0 + il) * N + (j0 + jl);
    pscale[pair] = (amax > 0.f) ? (amax / 32767.0f) : 0.f;

    int4* out = (int4*)(phiQ + pair * (C * C));
#pragma unroll
    for (int ci = 0; ci < C; ++ci) {
        int q[C];
#pragma unroll
        for (int cj = 0; cj < C; ++cj) q[cj] = (int)rintf(acc[ci][cj] * qs);
        int4 v;
        v.x = (q[0] & 0xFFFF) | (q[1] << 16);
        v.y = (q[2] & 0xFFFF) | (q[3] << 16);
        v.z = (q[4] & 0xFFFF) | (q[5] << 16);
        v.w = (q[6] & 0xFFFF) | (q[7] << 16);
        out[ci] = v;
    }
}

// ---------------- column sums ----------------

__global__ void colsum_part(const float* __restrict__ mbar, float* __restrict__ part) {
    int x = blockIdx.x * blockDim.x + threadIdx.x; // [0, N*C)
    int seg = blockIdx.y;                          // [0, SEG)
    float s = 0.f;
    int s0 = seg * (N / SEG);
#pragma unroll 4
    for (int k = 0; k < N / SEG; ++k) s += mbar[(size_t)(s0 + k) * N * C + x];
    part[(size_t)seg * (N * C) + x] = s;
}

__global__ void colsum_fin(const float* __restrict__ part, const float* __restrict__ psi,
                           float* __restrict__ incpsi) {
    int x = blockIdx.x * blockDim.x + threadIdx.x;
    if (x >= N * C) return;
    float s = psi[x];
#pragma unroll
    for (int g = 0; g < SEG; ++g) s += part[(size_t)g * (N * C) + x];
    incpsi[x] = s;
}

// ---------------- message update ----------------

__device__ __forceinline__ void damp_store(const float msg[C], const float mpv[C],
                                           float* __restrict__ mn) {
    float mx = msg[0];
#pragma unroll
    for (int c = 1; c < C; ++c) mx = fmaxf(mx, msg[c]);
    float e[C], s = 0.f;
#pragma unroll
    for (int c = 0; c < C; ++c) { e[c] = __expf(msg[c] - mx); s += e[c]; }
    float inv = DAMP / s;
    float o[C];
#pragma unroll
    for (int c = 0; c < C; ++c)
        o[c] = __logf(fmaf(e[c], inv, (1.f - DAMP) * __expf(mpv[c])));
    float4* w = (float4*)mn;
    w[0] = make_float4(o[0], o[1], o[2], o[3]);
    w[1] = make_float4(o[4], o[5], o[6], o[7]);
}

// one damped LBP sweep; thread = UNORDERED pair (i<=j): updates both directions
__global__ __launch_bounds__(256) void lbp_i16_sym(
    const short* __restrict__ phiQ, const float* __restrict__ pscale,
    const float* __restrict__ mprev, float* __restrict__ mnext,
    const float* __restrict__ incpsi)
{
    int i = blockIdx.y;
    int j = blockIdx.x * 256 + threadIdx.x;
    if (j < i) return;
    size_t pij = (size_t)i * N + j, pji = (size_t)j * N + i;

    const float4* mp_ij = (const float4*)(mprev + pij * C);
    float4 a0 = mp_ij[0], a1 = mp_ij[1];
    float mij[C] = {a0.x, a0.y, a0.z, a0.w, a1.x, a1.y, a1.z, a1.w};
    float mji[C];
    if (j > i) {
        const float4* mp_ji = (const float4*)(mprev + pji * C);
        float4 b0 = mp_ji[0], b1 = mp_ji[1];
        mji[0]=b0.x; mji[1]=b0.y; mji[2]=b0.z; mji[3]=b0.w;
        mji[4]=b1.x; mji[5]=b1.y; mji[6]=b1.z; mji[7]=b1.w;
    } else {
#pragma unroll
        for (int c = 0; c < C; ++c) mji[c] = mij[c];
    }

    float sci[C], scj[C];
#pragma unroll
    for (int c = 0; c < C; ++c) {
        sci[c] = incpsi[i * C + c] - mji[c];  // for message i->j (max over ci)
        scj[c] = incpsi[j * C + c] - mij[c];  // for message j->i (max over cj)
    }

    float s = pscale[pij];
    float msg_ij[C], msg_ji[C];
#pragma unroll
    for (int c = 0; c < C; ++c) { msg_ij[c] = -1e30f; msg_ji[c] = -1e30f; }

    const int4* p4 = (const int4*)(phiQ + pij * (C * C));
#pragma unroll
    for (int ci = 0; ci < C; ++ci) {
        int4 v = p4[ci];
        float ph[C];
        ph[0] = (float)((int)(short)(v.x & 0xFFFF)) * s;
        ph[1] = (float)(v.x >> 16) * s;
        ph[2] = (float)((int)(short)(v.y & 0xFFFF)) * s;
        ph[3] = (float)(v.y >> 16) * s;
        ph[4] = (float)((int)(short)(v.z & 0xFFFF)) * s;
        ph[5] = (float)(v.z >> 16) * s;
        ph[6] = (float)((int)(short)(v.w & 0xFFFF)) * s;
        ph[7] = (float)(v.w >> 16) * s;
#pragma unroll
        for (int cj = 0; cj < C; ++cj) {
            msg_ij[cj] = fmaxf(msg_ij[cj], sci[ci] + ph[cj]);   // phi[i,j,ci,cj]
            msg_ji[ci] = fmaxf(msg_ji[ci], scj[cj] + ph[cj]);   // phi[j,i,cj,ci] = phi[i,j,ci,cj]
        }
    }

    damp_store(msg_ij, mij, mnext + pij * C);
    if (j > i) damp_store(msg_ji, mji, mnext + pji * C);
}

// fallback: recompute phi tile fused with the message update (no phi buffer)
__global__ __launch_bounds__(256) void lbp_fused(
    const float* __restrict__ E, const float* __restrict__ F,
    const float* __restrict__ R, const float* __restrict__ D,
    const float* __restrict__ mprev, float* __restrict__ mnext,
    const float* __restrict__ incpsi)
{
    __shared__ PhiShared sh;
    int tid = threadIdx.x;
    int i0 = blockIdx.y * TI, j0 = blockIdx.x * TJ;
    int il = tid >> 4, jl = tid & 15;
    float acc[C][C];
    phi_compute(sh, E, F, R, D, i0, j0, il, jl, tid, acc);

    int i = i0 + il, j = j0 + jl;
    size_t pij = (size_t)i * N + j, pji = (size_t)j * N + i;
    float sc[C], mij[C];
#pragma unroll
    for (int c = 0; c < C; ++c) {
        sc[c] = incpsi[i * C + c] - mprev[pji * C + c];
        mij[c] = mprev[pij * C + c];
    }
    float msg[C];
#pragma unroll
    for (int cj = 0; cj < C; ++cj) msg[cj] = sc[0] + acc[0][cj];
#pragma unroll
    for (int ci = 1; ci < C; ++ci)
#pragma unroll
        for (int cj = 0; cj < C; ++cj) msg[cj] = fmaxf(msg[cj], sc[ci] + acc[ci][cj]);
    damp_store(msg, mij, mnext + pij * C);
}

// out[i,:] = softmax(psi + incoming - mbar[i,i,:])
__global__ void final_kernel(const float* __restrict__ incpsi, const float* __restrict__ mbar,
                             float* __restrict__ out) {
    int i = blockIdx.x * blockDim.x + threadIdx.x;
    if (i >= N) return;
    float u[C];
    float mx = -1e30f;
#pragma unroll
    for (int c = 0; c < C; ++c) {
        u[c] = incpsi[i * C + c] - mbar[((size_t)i * N + i) * C + c];
        mx = fmaxf(mx, u[c]);
    }
    float s = 0.f;
#pragma unroll
    for (int c = 0; c < C; ++c) { u[c] = __expf(u[c] - mx); s += u[c]; }
    float inv = 1.f / s;
#pragma unroll
    for (int c = 0; c < C; ++c) out[i * C + c] = u[c] * inv;
}

// ---------------- host ----------------

extern "C" void kernel_launch(void* const* d_in, const int* in_sizes, int n_in,
                              void* d_out, int out_size, void* d_ws, size_t ws_size,
                              hipStream_t stream) {
    const float* E  = (const float*)d_in[0];
    const float* F  = (const float*)d_in[1];
    const float* Fc = (const float*)d_in[2];
    const float* B  = (const float*)d_in[3];
    const float* R  = (const float*)d_in[4];
    const float* D  = (const float*)d_in[5];
    float* out = (float*)d_out;

    const size_t PHI_I16 = 134217728ull;  // N*N*C*C*2 (upper triangle touched)
    const size_t PSCALE  = 4194304ull;    // N*N*4
    const size_t MBAR    = 33554432ull;   // N*N*C*4
    const size_t SMALL   = 65536ull + 1048576ull;
    const size_t needQ = PHI_I16 + PSCALE + 2 * MBAR + SMALL; // ~206.6 MB

    int path = (ws_size >= needQ) ? 1 : 2;

    char* p = (char*)d_ws;
    size_t off = (path == 1) ? (PHI_I16 + PSCALE) : 0;
    short* phiQ   = (short*)p;
    float* pscale = (float*)(p + PHI_I16);
    float* mbar0 = (float*)(p + off);
    float* mbar1 = (float*)(p + off + MBAR);
    float* psi    = (float*)(p + off + 2 * MBAR);
    float* incpsi = psi + N * C;
    float* part   = (float*)(p + off + 2 * MBAR + 65536ull);

    psi_kernel<<<dim3((N * C + 255) / 256), 256, 0, stream>>>(E, Fc, B, psi);
    if (path == 1)
        phi_i16_sym_kernel<<<dim3(N / TJ, N / TI), 256, 0, stream>>>(E, F, R, D, phiQ, pscale);

    zero4_kernel<<<dim3((N * N * C / 4 + 255) / 256), 256, 0, stream>>>((float4*)mbar0, N * N * C / 4);

    float* cur = mbar0;
    float* nxt = mbar1;
    for (int it = 0; it < LBP_LOOPS; ++it) {
        colsum_part<<<dim3((N * C) / 256, SEG), 256, 0, stream>>>(cur, part);
        colsum_fin<<<dim3((N * C) / 256), 256, 0, stream>>>(part, psi, incpsi);
        if (path == 1)
            lbp_i16_sym<<<dim3(N / 256, N), 256, 0, stream>>>(phiQ, pscale, cur, nxt, incpsi);
        else
            lbp_fused<<<dim3(N / TJ, N / TI), 256, 0, stream>>>(E, F, R, D, cur, nxt, incpsi);
        float* t = cur; cur = nxt; nxt = t;
    }
    colsum_part<<<dim3((N * C) / 256, SEG), 256, 0, stream>>>(cur, part);
    colsum_fin<<<dim3((N * C) / 256), 256, 0, stream>>>(part, psi, incpsi);
    final_kernel<<<dim3((N + 255) / 256), 256, 0, stream>>>(incpsi, cur, out);
}

// Round 5
// 566.590 us; speedup vs baseline: 1.4282x; 1.2899x over previous
//
#include <hip/hip_runtime.h>
#include <math.h>

#define N 1024
#define C 8
#define DIM 128
#define K 3
#define LBP_LOOPS 10
#define DAMP 0.5f

#define TI 16
#define TJ 16
#define DCH 32
#define ESTRIDE 257   // ODD -> forces scalar ds_read, conflict-free (round-3 evidence)
#define FSTRIDE 129
#define SR 136        // staged message row stride (floats)
#define NT 64         // N/16 tiles per dim

// triangular pair index for i<=j
__device__ __forceinline__ size_t tri_idx(int i, int j) {
    return (size_t)i * N - (((size_t)i * (i - 1)) >> 1) + (size_t)(j - i);
}

// ---------------- small utility kernels ----------------

__global__ void zero4_kernel(float4* __restrict__ p, int n4) {
    int x = blockIdx.x * blockDim.x + threadIdx.x;
    if (x < n4) p[x] = make_float4(0.f, 0.f, 0.f, 0.f);
}

// psi[i,c] = sum_d E[i,c,d]*B[d]*Fc[i,d]
__global__ void psi_kernel(const float* __restrict__ E, const float* __restrict__ Fc,
                           const float* __restrict__ B, float* __restrict__ psi) {
    int x = blockIdx.x * blockDim.x + threadIdx.x; // [0, N*C)
    if (x >= N * C) return;
    int i = x / C;
    const float* e = E + (size_t)x * DIM;
    const float* fc = Fc + (size_t)i * DIM;
    float s = 0.f;
#pragma unroll 8
    for (int d = 0; d < DIM; ++d) s = fmaf(e[d] * B[d], fc[d], s);
    psi[x] = s;
}

// ---------------- phi builder ----------------

// Union layout: phase 1 = sFi/sFj (stride 129); phase 2 = sEi/sEj (stride 257).
// 2*16*257*4 + 2*K*DIM*4 = 35,968 B -> 4 blocks/CU.
struct PhiShared {
    float sU[2 * TI * ESTRIDE];
    float sD[K * DIM];
    float sR[K * DIM];
};

__device__ __forceinline__ void phi_compute(
    PhiShared& sh,
    const float* __restrict__ E, const float* __restrict__ F,
    const float* __restrict__ R, const float* __restrict__ D,
    int i0, int j0, int il, int jl, int tid, float acc[C][C])
{
    float* sFi = sh.sU;
    float* sFj = sh.sU + TI * FSTRIDE;
    float* sEi = sh.sU;
    float* sEj = sh.sU + TI * ESTRIDE;

    for (int t = tid; t < TI * DIM; t += 256) {
        int r = t / DIM, d = t % DIM;
        sFi[r * FSTRIDE + d] = F[(size_t)(i0 + r) * DIM + d];
        sFj[r * FSTRIDE + d] = F[(size_t)(j0 + r) * DIM + d];
    }
    for (int t = tid; t < K * DIM; t += 256) { sh.sD[t] = D[t]; sh.sR[t] = R[t]; }
    __syncthreads();

    float lg0 = 0.f, lg1 = 0.f, lg2 = 0.f;
#pragma unroll 4
    for (int d = 0; d < DIM; ++d) {
        float ff = sFi[il * FSTRIDE + d] * sFj[jl * FSTRIDE + d];
        lg0 = fmaf(ff, sh.sD[d], lg0);
        lg1 = fmaf(ff, sh.sD[DIM + d], lg1);
        lg2 = fmaf(ff, sh.sD[2 * DIM + d], lg2);
    }
    const float scale = 0.088388347648318447f; // 1/sqrt(128)
    lg0 *= scale; lg1 *= scale; lg2 *= scale;
    float mx = fmaxf(fmaxf(lg0, lg1), lg2);
    float e0 = __expf(lg0 - mx), e1 = __expf(lg1 - mx), e2 = __expf(lg2 - mx);
    float inv = 1.f / (e0 + e1 + e2);
    float a0 = e0 * inv, a1 = e1 * inv, a2 = e2 * inv;

#pragma unroll
    for (int ci = 0; ci < C; ++ci)
#pragma unroll
        for (int cj = 0; cj < C; ++cj) acc[ci][cj] = 0.f;

    for (int d0 = 0; d0 < DIM; d0 += DCH) {
        __syncthreads();  // previous readers of sU done
        for (int t = tid; t < TI * C * DCH; t += 256) {
            int loc = t >> 8;
            int ci = (t >> 5) & 7;
            int d = t & 31;
            sEi[loc * ESTRIDE + ci * DCH + d] = E[((size_t)(i0 + loc) * C + ci) * DIM + d0 + d];
            sEj[loc * ESTRIDE + ci * DCH + d] = E[((size_t)(j0 + loc) * C + ci) * DIM + d0 + d];
        }
        __syncthreads();
#pragma unroll 4
        for (int d = 0; d < DCH; ++d) {
            float rw = a0 * sh.sR[d0 + d] + a1 * sh.sR[DIM + d0 + d] + a2 * sh.sR[2 * DIM + d0 + d];
            float ei[C], ej[C];
#pragma unroll
            for (int ci = 0; ci < C; ++ci) ei[ci] = sEi[il * ESTRIDE + ci * DCH + d] * rw;
#pragma unroll
            for (int cj = 0; cj < C; ++cj) ej[cj] = sEj[jl * ESTRIDE + cj * DCH + d];
#pragma unroll
            for (int ci = 0; ci < C; ++ci)
#pragma unroll
                for (int cj = 0; cj < C; ++cj)
                    acc[ci][cj] = fmaf(ei[ci], ej[cj], acc[ci][cj]);
        }
    }
}

// int16 phi, per-pair scale, triangular-packed (i<=j only)
__global__ __launch_bounds__(256) void phi_i16_sym_kernel(
    const float* __restrict__ E, const float* __restrict__ F,
    const float* __restrict__ R, const float* __restrict__ D,
    short* __restrict__ phiQ, float* __restrict__ pscale)
{
    int i0 = blockIdx.y * TI, j0 = blockIdx.x * TJ;
    if (i0 > j0) return;
    __shared__ PhiShared sh;
    int tid = threadIdx.x;
    int il = tid >> 4, jl = tid & 15;
    float acc[C][C];
    phi_compute(sh, E, F, R, D, i0, j0, il, jl, tid, acc);

    int i = i0 + il, j = j0 + jl;
    if (i > j) return;  // after all syncthreads

    float amax = 0.f;
#pragma unroll
    for (int ci = 0; ci < C; ++ci)
#pragma unroll
        for (int cj = 0; cj < C; ++cj) amax = fmaxf(amax, fabsf(acc[ci][cj]));
    float qs = (amax > 0.f) ? (32767.0f / amax) : 1.0f;

    size_t tri = tri_idx(i, j);
    pscale[tri] = (amax > 0.f) ? (amax / 32767.0f) : 0.f;

    int4* out = (int4*)(phiQ + tri * (C * C));
#pragma unroll
    for (int ci = 0; ci < C; ++ci) {
        int q[C];
#pragma unroll
        for (int cj = 0; cj < C; ++cj) q[cj] = (int)rintf(acc[ci][cj] * qs);
        int4 v;
        v.x = (q[0] & 0xFFFF) | (q[1] << 16);
        v.y = (q[2] & 0xFFFF) | (q[3] << 16);
        v.z = (q[4] & 0xFFFF) | (q[5] << 16);
        v.w = (q[6] & 0xFFFF) | (q[7] << 16);
        out[ci] = v;
    }
}

// ---------------- message update core ----------------

__device__ __forceinline__ void damp_calc(const float msg[C], const float mpv[C], float o[C]) {
    float mx = msg[0];
#pragma unroll
    for (int c = 1; c < C; ++c) mx = fmaxf(mx, msg[c]);
    float e[C], s = 0.f;
#pragma unroll
    for (int c = 0; c < C; ++c) { e[c] = __expf(msg[c] - mx); s += e[c]; }
    float inv = DAMP / s;
#pragma unroll
    for (int c = 0; c < C; ++c)
        o[c] = __logf(fmaf(e[c], inv, (1.f - DAMP) * __expf(mpv[c])));
}

// Tiled symmetric sweep. Block = 16x16 pair tile (upper-tri). All global I/O
// coalesced; transposes staged in LDS. Also emits per-(src_tile,dest) partial
// column sums -> partInc[64][N*C] (unique writer per slot, deterministic).
__global__ __launch_bounds__(256) void lbp_tile(
    const short* __restrict__ phiQ, const float* __restrict__ pscale,
    const float* __restrict__ mprev, float* __restrict__ mnext,
    const float* __restrict__ incpsi, float* __restrict__ partInc)
{
    int ti = blockIdx.y, tj = blockIdx.x;
    if (tj < ti) return;
    bool diag = (ti == tj);
    __shared__ __align__(16) float sA[16 * SR];
    __shared__ __align__(16) float sB[16 * SR];
    __shared__ float sInc[256];
    int tid = threadIdx.x;
    int i0 = ti * 16, j0 = tj * 16;

    // stage mprev tiles (coalesced float4 rows)
    {
        const float4* __restrict__ src = (const float4*)mprev;
        for (int t = tid; t < 512; t += 256) {
            int row = t >> 5, rem = t & 31;
            float4 v = src[((size_t)(i0 + row) * N + j0) * 2 + rem];
            *(float4*)&sA[row * SR + rem * 4] = v;
        }
        if (!diag) {
            for (int t = tid; t < 512; t += 256) {
                int row = t >> 5, rem = t & 31;
                float4 v = src[((size_t)(j0 + row) * N + i0) * 2 + rem];
                *(float4*)&sB[row * SR + rem * 4] = v;
            }
        }
        if (tid < 128) sInc[tid] = incpsi[i0 * C + tid];
        else sInc[tid] = incpsi[j0 * C + (tid - 128)];
    }
    __syncthreads();

    int il = tid >> 4, jl = tid & 15;
    int i = i0 + il, j = j0 + jl;
    bool active = (!diag) || (jl >= il);
    bool dopair = active && (j > i);
    const float* sBB = diag ? sA : sB;

    float out_ij[C], out_ji[C];
    if (active) {
        float mij[C], mji[C], sci[C], scj[C];
#pragma unroll
        for (int c = 0; c < C; ++c) {
            mij[c] = sA[il * SR + jl * 8 + c];
            mji[c] = sBB[jl * SR + il * 8 + c];
            sci[c] = sInc[il * 8 + c] - mji[c];       // for message i->j
            scj[c] = sInc[128 + jl * 8 + c] - mij[c]; // for message j->i
        }

        size_t tri = tri_idx(i, j);
        float s = pscale[tri];
        float msg_ij[C], msg_ji[C];
#pragma unroll
        for (int c = 0; c < C; ++c) { msg_ij[c] = -1e30f; msg_ji[c] = -1e30f; }

        const int4* p4 = (const int4*)(phiQ + tri * (C * C));
#pragma unroll
        for (int ci = 0; ci < C; ++ci) {
            int4 v = p4[ci];
            float ph[C];
            ph[0] = (float)((int)(short)(v.x & 0xFFFF)) * s;
            ph[1] = (float)(v.x >> 16) * s;
            ph[2] = (float)((int)(short)(v.y & 0xFFFF)) * s;
            ph[3] = (float)(v.y >> 16) * s;
            ph[4] = (float)((int)(short)(v.z & 0xFFFF)) * s;
            ph[5] = (float)(v.z >> 16) * s;
            ph[6] = (float)((int)(short)(v.w & 0xFFFF)) * s;
            ph[7] = (float)(v.w >> 16) * s;
#pragma unroll
            for (int cj = 0; cj < C; ++cj) {
                msg_ij[cj] = fmaxf(msg_ij[cj], sci[ci] + ph[cj]); // phi[i,j,ci,cj]
                msg_ji[ci] = fmaxf(msg_ji[ci], scj[cj] + ph[cj]); // phi[j,i,cj,ci]
            }
        }
        damp_calc(msg_ij, mij, out_ij);
        if (dopair) damp_calc(msg_ji, mji, out_ji);
    }
    __syncthreads();  // all reads of sA/sB done

    // restage new messages: sA[src il][dest jl], sB[src jl][dest il]
    if (active) {
#pragma unroll
        for (int c = 0; c < C; ++c) sA[il * SR + jl * 8 + c] = out_ij[c];
        if (dopair) {
            if (diag) {
#pragma unroll
                for (int c = 0; c < C; ++c) sA[jl * SR + il * 8 + c] = out_ji[c];
            } else {
#pragma unroll
                for (int c = 0; c < C; ++c) sB[jl * SR + il * 8 + c] = out_ji[c];
            }
        }
    }
    __syncthreads();

    // coalesced writeout
    {
        float4* __restrict__ dst = (float4*)mnext;
        for (int t = tid; t < 512; t += 256) {
            int row = t >> 5, rem = t & 31;
            dst[((size_t)(i0 + row) * N + j0) * 2 + rem] = *(const float4*)&sA[row * SR + rem * 4];
        }
        if (!diag) {
            for (int t = tid; t < 512; t += 256) {
                int row = t >> 5, rem = t & 31;
                dst[((size_t)(j0 + row) * N + i0) * 2 + rem] = *(const float4*)&sB[row * SR + rem * 4];
            }
        }
    }

    // partial column sums (unique writer per slot)
    if (tid < 128) {
        int l = tid >> 3, c = tid & 7;
        float s = 0.f;
#pragma unroll
        for (int k = 0; k < 16; ++k) s += sA[k * SR + l * 8 + c];
        partInc[(size_t)ti * (N * C) + (j0 + l) * C + c] = s;
    } else if (!diag) {
        int t2 = tid - 128;
        int l = t2 >> 3, c = t2 & 7;
        float s = 0.f;
#pragma unroll
        for (int k = 0; k < 16; ++k) s += sB[k * SR + l * 8 + c];
        partInc[(size_t)tj * (N * C) + (i0 + l) * C + c] = s;
    }
}

// incpsi[x] = psi[x] + sum over 64 source-tiles of partInc
__global__ void incfin_kernel(const float* __restrict__ partInc, const float* __restrict__ psi,
                              float* __restrict__ incpsi) {
    int x = blockIdx.x * 256 + threadIdx.x;
    if (x >= N * C) return;
    float s = psi[x];
#pragma unroll 8
    for (int g = 0; g < NT; ++g) s += partInc[(size_t)g * (N * C) + x];
    incpsi[x] = s;
}

// out[i,:] = softmax(incpsi - mbar[i,i,:])
__global__ void final_kernel(const float* __restrict__ incpsi, const float* __restrict__ mbar,
                             float* __restrict__ out) {
    int i = blockIdx.x * blockDim.x + threadIdx.x;
    if (i >= N) return;
    float u[C];
    float mx = -1e30f;
#pragma unroll
    for (int c = 0; c < C; ++c) {
        u[c] = incpsi[i * C + c] - mbar[((size_t)i * N + i) * C + c];
        mx = fmaxf(mx, u[c]);
    }
    float s = 0.f;
#pragma unroll
    for (int c = 0; c < C; ++c) { u[c] = __expf(u[c] - mx); s += u[c]; }
    float inv = 1.f / s;
#pragma unroll
    for (int c = 0; c < C; ++c) out[i * C + c] = u[c] * inv;
}

// ---------------- host ----------------

extern "C" void kernel_launch(void* const* d_in, const int* in_sizes, int n_in,
                              void* d_out, int out_size, void* d_ws, size_t ws_size,
                              hipStream_t stream) {
    const float* E  = (const float*)d_in[0];
    const float* F  = (const float*)d_in[1];
    const float* Fc = (const float*)d_in[2];
    const float* B  = (const float*)d_in[3];
    const float* R  = (const float*)d_in[4];
    const float* D  = (const float*)d_in[5];
    float* out = (float*)d_out;

    const size_t NPAIR   = (size_t)N * (N + 1) / 2;        // 524,800
    const size_t PHI_SZ  = NPAIR * C * C * 2;              // 67,174,400
    const size_t PSC_SZ  = NPAIR * 4;                      //  2,099,200
    const size_t MBAR    = (size_t)N * N * C * 4;          // 33,554,432
    const size_t PART_SZ = (size_t)NT * N * C * 4;         //  2,097,152

    char* p = (char*)d_ws;
    short* phiQ   = (short*)p;                     p += PHI_SZ;
    float* pscale = (float*)p;                     p += PSC_SZ;
    float* mbar0  = (float*)p;                     p += MBAR;
    float* mbar1  = (float*)p;                     p += MBAR;
    float* partInc= (float*)p;                     p += PART_SZ;
    float* psi    = (float*)p;                     p += (size_t)N * C * 4;
    float* incpsi = (float*)p;                     // total ~138.7 MB

    psi_kernel<<<dim3((N * C + 255) / 256), 256, 0, stream>>>(E, Fc, B, psi);
    phi_i16_sym_kernel<<<dim3(N / TJ, N / TI), 256, 0, stream>>>(E, F, R, D, phiQ, pscale);
    zero4_kernel<<<dim3((N * N * C / 4 + 255) / 256), 256, 0, stream>>>((float4*)mbar0, N * N * C / 4);

    float* cur = mbar0;
    float* nxt = mbar1;
    const float* incp = psi;  // iteration 0: incoming = 0
    for (int it = 0; it < LBP_LOOPS; ++it) {
        lbp_tile<<<dim3(NT, NT), 256, 0, stream>>>(phiQ, pscale, cur, nxt, incp, partInc);
        incfin_kernel<<<dim3((N * C + 255) / 256), 256, 0, stream>>>(partInc, psi, incpsi);
        incp = incpsi;
        float* t = cur; cur = nxt; nxt = t;
    }
    final_kernel<<<dim3((N + 255) / 256), 256, 0, stream>>>(incpsi, cur, out);
}